// Round 7
// baseline (315.062 us; speedup 1.0000x reference)
//
#include <hip/hip_runtime.h>
#include <hip/hip_fp16.h>

#define HID 64
#define NGRAPHS 256

typedef _Float16 half8 __attribute__((ext_vector_type(8)));
typedef float f32x4 __attribute__((ext_vector_type(4)));

// MEASURED LAWS (R1-R25):
//  - R1: scattered device-scope stores ~0.9 TB/s through 64B lines;
//    SAME-LINE fp32 atomics ~15 G/s (line-serialized). Line-parallel
//    atomics over L2-resident arrays are NOT covered by that law.
//  - R13: grid.sync() ~100us at full grid -> discrete launches win.
//  - R14/R21: narrow-grid fusion serializes wide phases. R17: same-grid
//    fusion wins. R15: >8-wide gather unroll regresses.
//  - R19 DISASTER: device-scope atomics+fences INSIDE a wide gather
//    kernel poison L2 gather throughput (4x). Standalone atomic kernels
//    are a different regime.
//  - R20: per-block partials + tiny pool launch. R21: cooperative csr
//    loads ~-20us. R22: LINEARITY pass 1 (32B x~ rows). R23: LINEARITY
//    tail (z = dinv*(relu2@(W3@Wl)), 8B rows). 197us.
//  - R24: gather instruction-count reduction was NEUTRAL -> gather
//    passes are MLP-saturated/latency-walled, not instruction-bound.
//    Pass-2's 12.8MB random-row table is near the L2/L3 random wall.
// R25: replace 4-kernel bucket-sort CSR (hist/scan/scatter/csr_build,
//    ~39us, 3x dst reads + 10MB packed round-trip) with direct build:
//    memset(deg) + k_deg (atomic degree hist, 100K L2-resident counters,
//    ~12.5 ops/line -> line-parallel) + k_scan2 (rowptr partials + dinv
//    + x~ tail) + k_scatter2 (fixup + atomic slot scatter; csr stores
//    write-combine in L2, 5MB << 32MB). Edge order in a row becomes
//    nondeterministic (sum-order rounding only).

// ---- P0: prepW + W3l=W3@Wl + atomic degree histogram --------------------

__global__ __launch_bounds__(256) void k_deg(
        const int* __restrict__ dst, const float* __restrict__ W2,
        const float* __restrict__ W3, const float* __restrict__ Wl,
        __half* __restrict__ Wf2, float* __restrict__ W3l,
        int* __restrict__ deg, float* __restrict__ gsum, int e) {
    const int t = threadIdx.x, b = blockIdx.x;
    const int gtid = b * 256 + t;
    if (gtid < 512) {       // W2 fragment repack: 16x16x32-f16 B layout
        int p = gtid;
        int kt = p >> 8, c = (p >> 6) & 3, lane = p & 63;
        int quad = lane >> 4, m = lane & 15;
#pragma unroll
        for (int j = 0; j < 8; ++j) {
            int k = kt * 32 + quad * 8 + j;
            int ch = c * 16 + m;
            Wf2[(size_t)p * 8 + j] = __float2half(W2[k * HID + ch]);
        }
    }
    if (b == 0) {
        for (int i = t; i < NGRAPHS * 2; i += 256) gsum[i] = 0.0f;
        if (t < 128) {      // W3l[j][o] = sum_k W3[j][k]*Wl[k][o]
            int j = t >> 1, o = t & 1;
            float s = 0.0f;
#pragma unroll
            for (int k = 0; k < HID; ++k) s += W3[j * HID + k] * Wl[k * 2 + o];
            W3l[j * 2 + o] = s;
        }
    }
    int idx = b * 1024 + t * 4;
    if (idx + 3 < e) {
        int4 d = *(const int4*)(dst + idx);
        atomicAdd(&deg[d.x], 1);
        atomicAdd(&deg[d.y], 1);
        atomicAdd(&deg[d.z], 1);
        atomicAdd(&deg[d.w], 1);
    } else {
        for (int i = idx; i < e && i < idx + 4; ++i)
            atomicAdd(&deg[dst[i]], 1);
    }
}

// ---- P1: scan deg (512 nodes/block) -> partial rowptr + wpcnt + bsum;
//          per-node dinv + x~ = x*dinv tail (all node-local) ------------

__global__ __launch_bounds__(256) void k_scan2(
        const int* __restrict__ deg, const float* __restrict__ x,
        int* __restrict__ rowptr, int* __restrict__ wpcnt,
        int* __restrict__ bsum, float* __restrict__ dinv,
        float* __restrict__ xt, int n) {
    __shared__ int sh[256];
    __shared__ int degS[512];
    const int t = threadIdx.x, b = blockIdx.x;
    const int base = b * 512;
    const int i0 = base + 2 * t, i1 = i0 + 1;
    int v0 = (i0 < n) ? deg[i0] : 0;
    int v1 = (i1 < n) ? deg[i1] : 0;
    degS[2 * t] = v0;
    degS[2 * t + 1] = v1;
    int s = v0 + v1;
    sh[t] = s;
    __syncthreads();
#pragma unroll
    for (int o = 1; o < 256; o <<= 1) {
        int add = (t >= o) ? sh[t - o] : 0;
        __syncthreads();
        sh[t] += add;
        __syncthreads();
    }
    int run = sh[t] - s;
    if (i0 < n) {
        rowptr[i0] = run;  wpcnt[i0] = run;
        dinv[i0] = rsqrtf((float)(v0 + 1));
    }
    if (i1 < n) {
        rowptr[i1] = run + v0;  wpcnt[i1] = run + v0;
        dinv[i1] = rsqrtf((float)(v1 + 1));
    }
    if (t == 255) bsum[b] = sh[255];
    __syncthreads();
    // x~ tail: node-local, 8 floats/node
    for (int i = t; i < 512 * 8; i += 256) {
        int nl = i >> 3, k = i & 7;
        int node = base + nl;
        if (node < n)
            xt[(size_t)node * 8 + k] =
                (k < 7) ? x[(size_t)node * 7 + k] * rsqrtf((float)(degS[nl] + 1))
                        : 0.0f;
    }
}

// ---- P2: bscan fixup of rowptr (in-place) + atomic slot scatter ---------

__global__ __launch_bounds__(256) void k_scatter2(
        const int* __restrict__ src, const int* __restrict__ dst,
        int* __restrict__ rowptr, const int* __restrict__ bsum,
        int* __restrict__ wpcnt, int* __restrict__ csr,
        int e, int n, int nscan) {
    __shared__ int bscan[256];
    const int t = threadIdx.x, b = blockIdx.x;
    bscan[t] = (t < nscan) ? bsum[t] : 0;
    __syncthreads();
#pragma unroll
    for (int o = 1; o < 256; o <<= 1) {
        int add = (t >= o) ? bscan[t - o] : 0;
        __syncthreads();
        bscan[t] += add;
        __syncthreads();
    }
    // fixup: rowptr[i] += prefix(bsum) -- each i touched by exactly one thread
    for (int i = b * 256 + t; i < n; i += gridDim.x * 256) {
        int q = i >> 9;
        rowptr[i] += (q ? bscan[q - 1] : 0);
    }
    if (b == 0 && t == 0) rowptr[n] = e;
    // per-edge atomic slot scatter (wpcnt holds PARTIAL base; add bscan here)
    int idx = b * 1024 + t * 4;
    if (idx + 3 < e) {
        int4 d = *(const int4*)(dst + idx);
        int4 s = *(const int4*)(src + idx);
        int q0 = d.x >> 9, q1 = d.y >> 9, q2 = d.z >> 9, q3 = d.w >> 9;
        int o0 = q0 ? bscan[q0 - 1] : 0;
        int o1 = q1 ? bscan[q1 - 1] : 0;
        int o2 = q2 ? bscan[q2 - 1] : 0;
        int o3 = q3 ? bscan[q3 - 1] : 0;
        int p0 = atomicAdd(&wpcnt[d.x], 1);
        int p1 = atomicAdd(&wpcnt[d.y], 1);
        int p2 = atomicAdd(&wpcnt[d.z], 1);
        int p3 = atomicAdd(&wpcnt[d.w], 1);
        csr[p0 + o0] = s.x;
        csr[p1 + o1] = s.y;
        csr[p2 + o2] = s.z;
        csr[p3 + o3] = s.w;
    } else {
        for (int i = idx; i < e && i < idx + 4; ++i) {
            int dd = dst[i];
            int q = dd >> 9;
            int o = q ? bscan[q - 1] : 0;
            int p = atomicAdd(&wpcnt[dd], 1);
            csr[p + o] = src[i];
        }
    }
}

__device__ __forceinline__ void add_h8(float* a, int4 raw) {
    const __half2* p = (const __half2*)&raw;
#pragma unroll
    for (int i = 0; i < 4; ++i) {
        float2 f = __half22float2(p[i]);
        a[2 * i] += f.x;
        a[2 * i + 1] += f.y;
    }
}

// ---- FUSED layers 1+2 (R24): lane-per-edge x~ row gather + W1 + MFMA ----

__global__ __launch_bounds__(256) void k_aggx_gemm(
        const int* __restrict__ rowptr, const int* __restrict__ csr,
        const float* __restrict__ xt, const float* __restrict__ b,
        const float* __restrict__ dinv, const float* __restrict__ W1,
        const __half* __restrict__ Wf, __half* __restrict__ hout,
        int n_nodes) {
    __shared__ __half act[16 * 72];
    __shared__ float W1s[7 * HID];
    const int t = threadIdx.x;
    const int n0 = blockIdx.x * 16;
    const int nl = t >> 4;          // local node 0..15
    const int node = n0 + nl;
    const int l16 = t & 15;
    const float4* xt4 = (const float4*)xt;
    const float4* b4 = (const float4*)b;

    for (int i = t; i < 7 * HID; i += 256) W1s[i] = W1[i];

    float acc8[8];
#pragma unroll
    for (int i = 0; i < 8; ++i) acc8[i] = 0.0f;

    float4 av = make_float4(0.0f, 0.0f, 0.0f, 0.0f);
    float dv = 0.0f;
    if (node < n_nodes) {
        int beg = rowptr[node], end = rowptr[node + 1];
        dv = dinv[node];
        if (l16 == 0) {                    // self term, once
            float4 s0 = xt4[(size_t)node * 2];
            float4 s1 = xt4[(size_t)node * 2 + 1];
            acc8[0] += s0.x; acc8[1] += s0.y; acc8[2] += s0.z; acc8[3] += s0.w;
            acc8[4] += s1.x; acc8[5] += s1.y; acc8[6] += s1.z; acc8[7] += s1.w;
        }
        int j = beg;
        for (; j + 15 < end; j += 16) {    // 16 edges: 1 csr + 2 gathers
            int e = csr[j + l16];
            float4 r0 = xt4[(size_t)e * 2];
            float4 r1 = xt4[(size_t)e * 2 + 1];
            acc8[0] += r0.x; acc8[1] += r0.y; acc8[2] += r0.z; acc8[3] += r0.w;
            acc8[4] += r1.x; acc8[5] += r1.y; acc8[6] += r1.z; acc8[7] += r1.w;
        }
        int rem = end - j;
        if (l16 < rem) {
            int e = csr[j + l16];
            float4 r0 = xt4[(size_t)e * 2];
            float4 r1 = xt4[(size_t)e * 2 + 1];
            acc8[0] += r0.x; acc8[1] += r0.y; acc8[2] += r0.z; acc8[3] += r0.w;
            acc8[4] += r1.x; acc8[5] += r1.y; acc8[6] += r1.z; acc8[7] += r1.w;
        }
    }
    // 16-lane xor tree: every lane ends with the full 7-comp aggregate
#pragma unroll
    for (int o = 8; o; o >>= 1)
#pragma unroll
        for (int i = 0; i < 7; ++i)
            acc8[i] += __shfl_xor(acc8[i], o, 16);

    if (node < n_nodes) {
        float4 bb = b4[l16];
#pragma unroll
        for (int i = 0; i < 4; ++i) {
            int c = l16 * 4 + i;
            float dot = 0.0f;
#pragma unroll
            for (int k = 0; k < 7; ++k) dot += acc8[k] * W1s[k * HID + c];
            float v = ((const float*)&bb)[i] + dv * dot;
            ((float*)&av)[i] = fmaxf(v, 0.0f);     // relu -> gemm input
        }
    }
    {   // stage act tile: row nl, cols l16*4..+3 (8B store)
        __half2 p0 = __floats2half2_rn(av.x, av.y);
        __half2 p1 = __floats2half2_rn(av.z, av.w);
        int2 pk;
        pk.x = *(int*)&p0;
        pk.y = *(int*)&p1;
        *(int2*)&act[nl * 72 + l16 * 4] = pk;
    }
    __syncthreads();

    const int wave = t >> 6, lane = t & 63;
    const int quad = lane >> 4, m = lane & 15;
    const half8* Wf8 = (const half8*)Wf;
    f32x4 acc = {0.0f, 0.0f, 0.0f, 0.0f};
#pragma unroll
    for (int kt = 0; kt < 2; ++kt) {
        half8 a = *(const half8*)&act[m * 72 + kt * 32 + quad * 8];
        half8 bv = Wf8[(kt * 4 + wave) * 64 + lane];
        acc = __builtin_amdgcn_mfma_f32_16x16x32_f16(a, bv, acc, 0, 0, 0);
    }
#pragma unroll
    for (int r = 0; r < 4; ++r) {
        int nd = n0 + quad * 4 + r;
        if (nd < n_nodes)
            hout[(size_t)nd * HID + wave * 16 + m] =
                __float2half(acc[r] * dinv[nd]);
    }
}

// ---- pass 2: agg h2 via dwordx4 slices + relu2 + z epilogue -------------

__global__ __launch_bounds__(256) void k_agg_z(
        const int* __restrict__ rowptr, const int* __restrict__ csr,
        const __half* __restrict__ h, const float* __restrict__ b,
        const float* __restrict__ dinv, const float* __restrict__ W3l,
        float2* __restrict__ zbuf, int n_nodes) {
    const int t = threadIdx.x;
    const int n0 = blockIdx.x * 16;
    const int nl = t >> 4;          // local node 0..15
    const int node = n0 + nl;
    const int l16 = t & 15;
    const int cb = l16 & 7;         // my 8-channel block (16B slice)
    const int hf = l16 >> 3;        // even/odd edge half
    const int4* h16 = (const int4*)h;   // 16B units; row = 8 units

    float w3l0[8], w3l1[8], bb8[8];
#pragma unroll
    for (int i = 0; i < 8; ++i) {
        w3l0[i] = W3l[(cb * 8 + i) * 2 + 0];
        w3l1[i] = W3l[(cb * 8 + i) * 2 + 1];
        bb8[i] = b[cb * 8 + i];
    }

    float acc8[8];
#pragma unroll
    for (int i = 0; i < 8; ++i) acc8[i] = 0.0f;

    float dv = 0.0f;
    if (node < n_nodes) {
        int beg = rowptr[node], end = rowptr[node + 1];
        dv = dinv[node];
        if (hf == 0)                       // self h' slice, once
            add_h8(acc8, h16[(size_t)node * 8 + cb]);
        int j = beg;
        for (; j + 7 < end; j += 8) {      // 8 edges: 1 csr + 4 gathers
            int e8 = csr[j + (l16 & 7)];
            int4 r[4];
#pragma unroll
            for (int q = 0; q < 4; ++q) {
                int sid = __shfl(e8, 2 * q + hf, 8);
                r[q] = h16[(size_t)sid * 8 + cb];
            }
#pragma unroll
            for (int q = 0; q < 4; ++q) add_h8(acc8, r[q]);
        }
        if (j + 3 < end) {                 // 4 edges: 2 gathers
            int e4 = csr[j + (l16 & 3)];
            int4 r[2];
#pragma unroll
            for (int q = 0; q < 2; ++q) {
                int sid = __shfl(e4, 2 * q + hf, 4);
                r[q] = h16[(size_t)sid * 8 + cb];
            }
            add_h8(acc8, r[0]);
            add_h8(acc8, r[1]);
            j += 4;
        }
        for (; j < end; ++j)               // <=3 edges: half 0 only
            if (hf == 0) add_h8(acc8, h16[(size_t)csr[j] * 8 + cb]);
    }
    // combine even/odd halves (lanes l16 and l16^8 hold same cb)
#pragma unroll
    for (int i = 0; i < 8; ++i) acc8[i] += __shfl_xor(acc8[i], 8, 16);
    // relu2 + dot with W3l columns
    float p0 = 0.0f, p1 = 0.0f;
#pragma unroll
    for (int i = 0; i < 8; ++i) {
        float v = fmaxf(bb8[i] + dv * acc8[i], 0.0f);
        p0 += v * w3l0[i];
        p1 += v * w3l1[i];
    }
#pragma unroll
    for (int o = 4; o; o >>= 1) {
        p0 += __shfl_xor(p0, o, 16);
        p1 += __shfl_xor(p1, o, 16);
    }
    if (node < n_nodes && l16 == 0)
        zbuf[node] = make_float2(p0 * dv, p1 * dv);
}

// ---- pass 3: aggregate z (8B rows, L2-resident) -> graph partials -------

__global__ __launch_bounds__(256) void k_zagg_part(
        const int* __restrict__ rowptr, const int* __restrict__ csr,
        const float2* __restrict__ zbuf, const float* __restrict__ dinv,
        const int* __restrict__ batch, float* __restrict__ partv,
        int* __restrict__ partg, float* __restrict__ gsum, int n_nodes) {
    __shared__ float2 ys[16];
    __shared__ int bg[16];
    const int t = threadIdx.x;
    const int n0 = blockIdx.x * 16;
    const int nl = t >> 4;
    const int node = n0 + nl;
    const int q = t & 15;

    if (t < 16) {
        int nd = n0 + t;
        bg[t] = (nd < n_nodes) ? batch[nd] : -1;
    }

    float2 yv = make_float2(0.0f, 0.0f);
    if (node < n_nodes) {
        int beg = rowptr[node], end = rowptr[node + 1];
        float2 acc = make_float2(0.0f, 0.0f);
        if (q == 0) acc = zbuf[node];          // self-loop
        int j = beg;
        for (; j + 15 < end; j += 16) {        // 16 edges/iter, 1 gather instr
            int e = csr[j + q];
            float2 v = zbuf[e];
            acc.x += v.x; acc.y += v.y;
        }
        int rem = end - j;
        if (q < rem) {
            int e = csr[j + q];
            float2 v = zbuf[e];
            acc.x += v.x; acc.y += v.y;
        }
#pragma unroll
        for (int o = 8; o; o >>= 1) {
            acc.x += __shfl_xor(acc.x, o, 16);
            acc.y += __shfl_xor(acc.y, o, 16);
        }
        float dv = dinv[node];
        yv = make_float2(acc.x * dv, acc.y * dv);
    }
    if (q == 0) ys[nl] = yv;
    __syncthreads();

    if (t == 0) {           // run-length reduce 16 nodes -> <=2 graph slots
        const int g0 = bg[0];
        const int g15 = bg[15];
        float2 s0 = make_float2(0.0f, 0.0f), s1 = make_float2(0.0f, 0.0f);
        for (int i = 0; i < 16; ++i) {
            int g = bg[i];
            float2 v = ys[i];
            if (g == g0) { s0.x += v.x; s0.y += v.y; }
            else if (g == g15) { s1.x += v.x; s1.y += v.y; }
            else if (g >= 0) {                 // ~never (graph <=14 nodes)
                atomicAdd(&gsum[g * 2 + 0], v.x);
                atomicAdd(&gsum[g * 2 + 1], v.y);
            }
        }
        partv[(size_t)blockIdx.x * 4 + 0] = s0.x;
        partv[(size_t)blockIdx.x * 4 + 1] = s0.y;
        partv[(size_t)blockIdx.x * 4 + 2] = s1.x;
        partv[(size_t)blockIdx.x * 4 + 3] = s1.y;
        partg[blockIdx.x * 2 + 0] = g0;
        partg[blockIdx.x * 2 + 1] = (g15 != g0) ? g15 : -1;
    }
}

// ---- pool over float2 partials + head bias: one block per graph ---------

__global__ __launch_bounds__(256) void k_pool_head(
        const float* __restrict__ partv, const int* __restrict__ partg,
        const float* __restrict__ gsum, const int* __restrict__ batch,
        const float* __restrict__ b3, const float* __restrict__ Wl,
        const float* __restrict__ bl, float* __restrict__ out, int n_nodes) {
    int g = blockIdx.x;
    int lo = 0, hi = n_nodes;
    while (lo < hi) { int m = (lo + hi) >> 1; if (batch[m] < g) lo = m + 1; else hi = m; }
    int nstart = lo;
    hi = n_nodes;
    while (lo < hi) { int m = (lo + hi) >> 1; if (batch[m] < g + 1) lo = m + 1; else hi = m; }
    int nend = lo;

    const int t = threadIdx.x;
    float ax = 0.0f, ay = 0.0f;
    if (nend > nstart) {
        int b0 = nstart >> 4, b1 = (nend - 1) >> 4;
        for (int b = b0 + t; b <= b1; b += 256) {
            if (partg[b * 2 + 0] == g) { ax += partv[(size_t)b * 4 + 0]; ay += partv[(size_t)b * 4 + 1]; }
            if (partg[b * 2 + 1] == g) { ax += partv[(size_t)b * 4 + 2]; ay += partv[(size_t)b * 4 + 3]; }
        }
    }
    __shared__ float rx[256], ry[256];
    rx[t] = ax; ry[t] = ay;
    __syncthreads();
    for (int s2 = 128; s2; s2 >>= 1) {
        if (t < s2) { rx[t] += rx[t + s2]; ry[t] += ry[t + s2]; }
        __syncthreads();
    }
    if (t < 2) {
        float cntf = fmaxf((float)(nend - nstart), 1.0f);
        float s = ((t == 0) ? rx[0] : ry[0]) + gsum[g * 2 + t];
        float hb = 0.0f;                     // b3 @ Wl (column t)
        for (int c = 0; c < HID; ++c) hb += b3[c] * Wl[c * 2 + t];
        out[g * 2 + t] = s / cntf + hb + bl[t];
    }
}

// -------------------------------------------------------------------------

extern "C" void kernel_launch(void* const* d_in, const int* in_sizes, int n_in,
                              void* d_out, int out_size, void* d_ws, size_t ws_size,
                              hipStream_t stream) {
    const float* x     = (const float*)d_in[0];
    const int*   ei    = (const int*)d_in[1];
    const int*   batch = (const int*)d_in[2];
    const float* W1    = (const float*)d_in[3];
    const float* b1    = (const float*)d_in[4];
    const float* W2    = (const float*)d_in[5];
    const float* b2    = (const float*)d_in[6];
    const float* W3    = (const float*)d_in[7];
    const float* b3    = (const float*)d_in[8];
    const float* Wl    = (const float*)d_in[9];
    const float* bl    = (const float*)d_in[10];
    float* out = (float*)d_out;

    const int N = in_sizes[0] / 7;     // 100000
    const int E = in_sizes[1] / 2;     // 1250000
    const int* src = ei;
    const int* dst = ei + E;

    const int nscan = (N + 511) >> 9;              // 196 (<=256)
    const int nb_e  = (E + 1023) / 1024;           // 1221

    char* ws = (char*)d_ws;
    size_t off = 0;
    auto carve = [&](size_t bytes) {
        void* p = ws + off;
        off = (off + bytes + 255) & ~(size_t)255;
        return p;
    };
    int*    deg    = (int*)carve((size_t)N * 4);
    int*    wpcnt  = (int*)carve((size_t)N * 4);
    int*    rowptr = (int*)carve((size_t)(N + 1) * 4);
    int*    bsum   = (int*)carve(256 * 4);
    int*    csr    = (int*)carve((size_t)E * 4);
    float*  dinv   = (float*)carve((size_t)N * 4);
    __half* Wf2    = (__half*)carve(4096 * 2);
    float*  W3l    = (float*)carve(128 * 4);
    float*  gsum   = (float*)carve((size_t)NGRAPHS * 2 * 4);
    float*  xt     = (float*)carve((size_t)(N + 64) * 8 * 4);     // padded x~
    __half* bufB   = (__half*)carve((size_t)(N + 64) * HID * 2);  // +pad rows
    float2* zbuf   = (float2*)carve((size_t)(N + 64) * 8);

    const int nb_agg = (N + 15) / 16;      // 6250
    float* partv = (float*)carve((size_t)nb_agg * 4 * 4);
    int*   partg = (int*)carve((size_t)nb_agg * 2 * 4);

    // ---- direct CSR build (R25): deg -> scan -> atomic slot scatter
    hipMemsetAsync(deg, 0, (size_t)N * 4, stream);
    k_deg<<<nb_e, 256, 0, stream>>>(dst, W2, W3, Wl, Wf2, W3l, deg, gsum, E);
    k_scan2<<<nscan, 256, 0, stream>>>(deg, x, rowptr, wpcnt, bsum, dinv,
                                       xt, N);
    k_scatter2<<<nb_e, 256, 0, stream>>>(src, dst, rowptr, bsum, wpcnt, csr,
                                         E, N, nscan);

    // ---- fused layers 1+2 (x~ agg + W1 matvec + W2 MFMA) -> bufB
    k_aggx_gemm<<<nb_agg, 256, 0, stream>>>(rowptr, csr, xt, b1, dinv, W1,
                                            Wf2, bufB, N);
    // ---- pass 2: agg bufB + relu2 + z = dinv*(relu2@W3l) (8B/node)
    k_agg_z<<<nb_agg, 256, 0, stream>>>(rowptr, csr, bufB, b2, dinv, W3l,
                                        zbuf, N);
    // ---- pass 3: agg z (8B rows) -> per-block graph partials
    k_zagg_part<<<nb_agg, 256, 0, stream>>>(rowptr, csr, zbuf, dinv, batch,
                                            partv, partg, gsum, N);

    // ---- pool over partials + head (one block per graph)
    k_pool_head<<<NGRAPHS, 256, 0, stream>>>(partv, partg, gsum, batch,
                                             b3, Wl, bl, out, N);
}

// Round 8
// 195.165 us; speedup vs baseline: 1.6143x; 1.6143x over previous
//
#include <hip/hip_runtime.h>
#include <hip/hip_fp16.h>

#define HID 64
#define NGRAPHS 256
#define CHUNK 4096        // edges per pass-1 chunk (306 blocks > 256 CUs)
#define BKTSZ 512         // nodes per coarse bucket
#define BKTSH 9
#define PSH 17            // src fits in 17 bits (N <= 131072)
#define PMASK 0x1FFFF

typedef _Float16 half8 __attribute__((ext_vector_type(8)));
typedef float f32x4 __attribute__((ext_vector_type(4)));

// MEASURED LAWS (R1-R26):
//  - R1: scattered device-scope stores ~0.9 TB/s through 64B lines;
//    same-line fp32 atomics ~15 G/s.
//  - R25 (reconfirmed R1 the hard way): L2 does NOT write-combine
//    randomly scattered 4B stores -- each costs a full 64B line
//    writeback (k_scatter2: 88MB WRITE for 5MB of payload, 100us at
//    950 GB/s). The LDS counting-sort exists precisely to convert
//    scattered writes into coalesced runs. It is NOT removable.
//  - R13: grid.sync() ~100us at full grid -> discrete launches win.
//  - R14/R21: narrow-grid fusion serializes wide phases. R17: same-grid
//    fusion wins. R15: >8-wide gather unroll regresses.
//  - R18: slot-packed scatter + binary-search rebuild (60us) loses to
//    the 3-pass scan pipeline (~39us). Keep the scan.
//  - R19 DISASTER: device-scope atomics+fences inside a wide gather
//    kernel poison L2 gather throughput (4x).
//  - R20: per-block partials + tiny pool launch. R21: cooperative csr
//    loads ~-20us. R22: LINEARITY pass 1 (32B x~ rows). R23: LINEARITY
//    tail (z = dinv*(relu2@(W3@Wl)), 8B rows). 197us.
//  - R24: gather instruction-count reduction NEUTRAL -> gather passes
//    are MLP-saturated/latency-walled. Pass-2's 12.8MB random-row table
//    is at the L3 random-row wall (~1.6 TB/s effective).
// R26: revert R25's direct CSR build; restore the R24 kernel (195us,
//    verified best). Structure is at its measured floor: ~75us gather
//    (latency wall), ~39us CSR (best of 3 structures tried), ~45us
//    launch boundaries (R13: cheaper than any fusion alternative).

// ---- P0: prepW + W3l=W3@Wl (block 0) + per-chunk coarse histogram ------

__global__ __launch_bounds__(256) void k_hist(
        const int* __restrict__ dst, const float* __restrict__ W2,
        const float* __restrict__ W3, const float* __restrict__ Wl,
        __half* __restrict__ Wf2, float* __restrict__ W3l,
        int* __restrict__ H, float* __restrict__ gsum,
        int e, int nbkt, int nchunk) {
    __shared__ int cnt4[4][256];    // per-wave split: 4x less contention
    const int t = threadIdx.x, b = blockIdx.x;
    const int gtid = b * 256 + t;
    if (gtid < 512) {       // W2 fragment repack: 16x16x32-f16 B layout
        int p = gtid;
        int kt = p >> 8, c = (p >> 6) & 3, lane = p & 63;
        int quad = lane >> 4, m = lane & 15;
#pragma unroll
        for (int j = 0; j < 8; ++j) {
            int k = kt * 32 + quad * 8 + j;
            int ch = c * 16 + m;
            Wf2[(size_t)p * 8 + j] = __float2half(W2[k * HID + ch]);
        }
    }
    if (b == 0) {
        for (int i = t; i < NGRAPHS * 2; i += 256) gsum[i] = 0.0f;
        if (t < 128) {      // W3l[j][o] = sum_k W3[j][k]*Wl[k][o]
            int j = t >> 1, o = t & 1;
            float s = 0.0f;
#pragma unroll
            for (int k = 0; k < HID; ++k) s += W3[j * HID + k] * Wl[k * 2 + o];
            W3l[j * 2 + o] = s;
        }
    }
    for (int i = t; i < 1024; i += 256) ((int*)cnt4)[i] = 0;
    __syncthreads();
    const int w = t >> 6;
#pragma unroll
    for (int it = 0; it < CHUNK / 1024; ++it) {
        int idx = b * CHUNK + it * 1024 + t * 4;
        if (idx + 3 < e) {
            int4 d = *(const int4*)(dst + idx);
            atomicAdd(&cnt4[w][d.x >> BKTSH], 1);
            atomicAdd(&cnt4[w][d.y >> BKTSH], 1);
            atomicAdd(&cnt4[w][d.z >> BKTSH], 1);
            atomicAdd(&cnt4[w][d.w >> BKTSH], 1);
        } else {
            for (int i = idx; i < e && i < idx + 4; ++i)
                atomicAdd(&cnt4[w][dst[i] >> BKTSH], 1);
        }
    }
    __syncthreads();
    for (int i = t; i < nbkt; i += 256)
        H[i * nchunk + b] = cnt4[0][i] + cnt4[1][i] + cnt4[2][i] + cnt4[3][i];
}

// ---- P1: per-1024 partial exclusive scans + block sums ------------------

__global__ __launch_bounds__(256) void k_scan(const int* __restrict__ in,
                                              int* __restrict__ outp,
                                              int* __restrict__ bsum, int n) {
    __shared__ int sh[256];
    const int t = threadIdx.x;
    const int base = blockIdx.x * 1024 + t * 4;
    int v[4];
    int s = 0;
#pragma unroll
    for (int k = 0; k < 4; k++) {
        int i = base + k;
        v[k] = (i < n) ? in[i] : 0;
        s += v[k];
    }
    sh[t] = s;
    __syncthreads();
#pragma unroll
    for (int off = 1; off < 256; off <<= 1) {
        int add = (t >= off) ? sh[t - off] : 0;
        __syncthreads();
        sh[t] += add;
        __syncthreads();
    }
    int run = sh[t] - s;
#pragma unroll
    for (int k = 0; k < 4; k++) {
        int i = base + k;
        if (i < n) outp[i] = run;
        run += v[k];
    }
    if (t == 255) bsum[blockIdx.x] = sh[255];
}

// ---- P2: bucket scatter (packed 4B, coalesced runs) ---------------------

__global__ __launch_bounds__(256) void k_scatter(
        const int* __restrict__ src, const int* __restrict__ dst,
        const int* __restrict__ Hs, const int* __restrict__ bsum,
        int* __restrict__ packed, int e, int nbkt, int nchunk, int nscan) {
    __shared__ int off[256];
    __shared__ int lc[256];
    __shared__ int bscan[64];
    const int t = threadIdx.x, b = blockIdx.x;
    if (t < 64) bscan[t] = (t < nscan) ? bsum[t] : 0;
    __syncthreads();
#pragma unroll
    for (int o = 1; o < 64; o <<= 1) {
        int add = (t < 64 && t >= o) ? bscan[t - o] : 0;
        __syncthreads();
        if (t < 64) bscan[t] += add;
        __syncthreads();
    }
    for (int i = t; i < nbkt; i += 256) {
        int idx = i * nchunk + b;
        int q = idx >> 10;
        off[i] = Hs[idx] + (q ? bscan[q - 1] : 0);
        lc[i] = 0;
    }
    __syncthreads();
#pragma unroll
    for (int it = 0; it < CHUNK / 1024; ++it) {
        int idx = b * CHUNK + it * 1024 + t * 4;
        if (idx + 3 < e) {
            int4 d = *(const int4*)(dst + idx);
            int4 s = *(const int4*)(src + idx);
            int b0 = d.x >> BKTSH, b1 = d.y >> BKTSH;
            int b2 = d.z >> BKTSH, b3 = d.w >> BKTSH;
            int r0 = atomicAdd(&lc[b0], 1);
            int r1 = atomicAdd(&lc[b1], 1);
            int r2 = atomicAdd(&lc[b2], 1);
            int r3 = atomicAdd(&lc[b3], 1);
            packed[off[b0] + r0] = s.x | ((d.x & (BKTSZ - 1)) << PSH);
            packed[off[b1] + r1] = s.y | ((d.y & (BKTSZ - 1)) << PSH);
            packed[off[b2] + r2] = s.z | ((d.z & (BKTSZ - 1)) << PSH);
            packed[off[b3] + r3] = s.w | ((d.w & (BKTSZ - 1)) << PSH);
        } else {
            for (int i = idx; i < e && i < idx + 4; ++i) {
                int dd = dst[i];
                int bk = dd >> BKTSH;
                int r = atomicAdd(&lc[bk], 1);
                packed[off[bk] + r] = src[i] | ((dd & (BKTSZ - 1)) << PSH);
            }
        }
    }
}

// ---- P3: per-bucket local CSR build + tiny x~ = x*dinv tail -------------

__global__ __launch_bounds__(256) void k_csr_build(
        const int* __restrict__ packed, const int* __restrict__ Hs,
        const int* __restrict__ bsum, int* __restrict__ rowptr,
        float* __restrict__ dinv, int* __restrict__ csr,
        const float* __restrict__ x, float* __restrict__ xt,
        int e, int n, int nbkt, int nchunk, int nscan) {
    __shared__ int cnt[BKTSZ];
    __shared__ int pref[BKTSZ];
    __shared__ int ssum[256];
    __shared__ int cnt2[BKTSZ];
    __shared__ int bscan[64];
    const int t = threadIdx.x, bkt = blockIdx.x;
    if (t < 64) bscan[t] = (t < nscan) ? bsum[t] : 0;
    if (bkt == 0 && t == 0) rowptr[n] = e;
    cnt[t] = 0; cnt[t + 256] = 0;
    cnt2[t] = 0; cnt2[t + 256] = 0;
    __syncthreads();
#pragma unroll
    for (int o = 1; o < 64; o <<= 1) {
        int add = (t < 64 && t >= o) ? bscan[t - o] : 0;
        __syncthreads();
        if (t < 64) bscan[t] += add;
        __syncthreads();
    }
    int i0 = bkt * nchunk;
    int q0 = i0 >> 10;
    int segStart = Hs[i0] + (q0 ? bscan[q0 - 1] : 0);
    int segEnd = e;
    if (bkt + 1 < nbkt) {
        int i1 = (bkt + 1) * nchunk;
        int q1 = i1 >> 10;
        segEnd = Hs[i1] + (q1 ? bscan[q1 - 1] : 0);
    }
    for (int j = segStart + t; j < segEnd; j += 256)
        atomicAdd(&cnt[(packed[j] >> PSH) & (BKTSZ - 1)], 1);
    __syncthreads();
    int a0 = cnt[2 * t], a1 = cnt[2 * t + 1];
    int s = a0 + a1;
    ssum[t] = s;
    __syncthreads();
#pragma unroll
    for (int off = 1; off < 256; off <<= 1) {
        int add = (t >= off) ? ssum[t - off] : 0;
        __syncthreads();
        ssum[t] += add;
        __syncthreads();
    }
    int p = ssum[t] - s;
    pref[2 * t] = p;
    pref[2 * t + 1] = p + a0;
    __syncthreads();
    for (int i = t; i < BKTSZ; i += 256) {
        int node = bkt * BKTSZ + i;
        if (node < n) {
            rowptr[node] = segStart + pref[i];
            dinv[node] = rsqrtf((float)(cnt[i] + 1));   // +1 self-loop
        }
    }
    for (int j = segStart + t; j < segEnd; j += 256) {
        int pk = packed[j];
        int ld = (pk >> PSH) & (BKTSZ - 1);
        int r = atomicAdd(&cnt2[ld], 1);
        csr[segStart + pref[ld] + r] = pk & PMASK;
    }
    // ---- tail: x~[node] = x[node] * dinv[node], padded to 8 floats
    for (int i = t; i < BKTSZ * 8; i += 256) {
        int nl = i >> 3, k = i & 7;
        int node = bkt * BKTSZ + nl;
        if (node < n)
            xt[(size_t)node * 8 + k] =
                (k < 7) ? x[(size_t)node * 7 + k] * rsqrtf((float)(cnt[nl] + 1))
                        : 0.0f;
    }
}

__device__ __forceinline__ void add_h8(float* a, int4 raw) {
    const __half2* p = (const __half2*)&raw;
#pragma unroll
    for (int i = 0; i < 4; ++i) {
        float2 f = __half22float2(p[i]);
        a[2 * i] += f.x;
        a[2 * i + 1] += f.y;
    }
}

// ---- FUSED layers 1+2 (R24): lane-per-edge x~ row gather + W1 + MFMA ----

__global__ __launch_bounds__(256) void k_aggx_gemm(
        const int* __restrict__ rowptr, const int* __restrict__ csr,
        const float* __restrict__ xt, const float* __restrict__ b,
        const float* __restrict__ dinv, const float* __restrict__ W1,
        const __half* __restrict__ Wf, __half* __restrict__ hout,
        int n_nodes) {
    __shared__ __half act[16 * 72];
    __shared__ float W1s[7 * HID];
    const int t = threadIdx.x;
    const int n0 = blockIdx.x * 16;
    const int nl = t >> 4;          // local node 0..15
    const int node = n0 + nl;
    const int l16 = t & 15;
    const float4* xt4 = (const float4*)xt;
    const float4* b4 = (const float4*)b;

    for (int i = t; i < 7 * HID; i += 256) W1s[i] = W1[i];

    float acc8[8];
#pragma unroll
    for (int i = 0; i < 8; ++i) acc8[i] = 0.0f;

    float4 av = make_float4(0.0f, 0.0f, 0.0f, 0.0f);
    float dv = 0.0f;
    if (node < n_nodes) {
        int beg = rowptr[node], end = rowptr[node + 1];
        dv = dinv[node];
        if (l16 == 0) {                    // self term, once
            float4 s0 = xt4[(size_t)node * 2];
            float4 s1 = xt4[(size_t)node * 2 + 1];
            acc8[0] += s0.x; acc8[1] += s0.y; acc8[2] += s0.z; acc8[3] += s0.w;
            acc8[4] += s1.x; acc8[5] += s1.y; acc8[6] += s1.z; acc8[7] += s1.w;
        }
        int j = beg;
        for (; j + 15 < end; j += 16) {    // 16 edges: 1 csr + 2 gathers
            int e = csr[j + l16];
            float4 r0 = xt4[(size_t)e * 2];
            float4 r1 = xt4[(size_t)e * 2 + 1];
            acc8[0] += r0.x; acc8[1] += r0.y; acc8[2] += r0.z; acc8[3] += r0.w;
            acc8[4] += r1.x; acc8[5] += r1.y; acc8[6] += r1.z; acc8[7] += r1.w;
        }
        int rem = end - j;
        if (l16 < rem) {
            int e = csr[j + l16];
            float4 r0 = xt4[(size_t)e * 2];
            float4 r1 = xt4[(size_t)e * 2 + 1];
            acc8[0] += r0.x; acc8[1] += r0.y; acc8[2] += r0.z; acc8[3] += r0.w;
            acc8[4] += r1.x; acc8[5] += r1.y; acc8[6] += r1.z; acc8[7] += r1.w;
        }
    }
    // 16-lane xor tree: every lane ends with the full 7-comp aggregate
#pragma unroll
    for (int o = 8; o; o >>= 1)
#pragma unroll
        for (int i = 0; i < 7; ++i)
            acc8[i] += __shfl_xor(acc8[i], o, 16);

    if (node < n_nodes) {
        float4 bb = b4[l16];
#pragma unroll
        for (int i = 0; i < 4; ++i) {
            int c = l16 * 4 + i;
            float dot = 0.0f;
#pragma unroll
            for (int k = 0; k < 7; ++k) dot += acc8[k] * W1s[k * HID + c];
            float v = ((const float*)&bb)[i] + dv * dot;
            ((float*)&av)[i] = fmaxf(v, 0.0f);     // relu -> gemm input
        }
    }
    {   // stage act tile: row nl, cols l16*4..+3 (8B store)
        __half2 p0 = __floats2half2_rn(av.x, av.y);
        __half2 p1 = __floats2half2_rn(av.z, av.w);
        int2 pk;
        pk.x = *(int*)&p0;
        pk.y = *(int*)&p1;
        *(int2*)&act[nl * 72 + l16 * 4] = pk;
    }
    __syncthreads();

    const int wave = t >> 6, lane = t & 63;
    const int quad = lane >> 4, m = lane & 15;
    const half8* Wf8 = (const half8*)Wf;
    f32x4 acc = {0.0f, 0.0f, 0.0f, 0.0f};
#pragma unroll
    for (int kt = 0; kt < 2; ++kt) {
        half8 a = *(const half8*)&act[m * 72 + kt * 32 + quad * 8];
        half8 bv = Wf8[(kt * 4 + wave) * 64 + lane];
        acc = __builtin_amdgcn_mfma_f32_16x16x32_f16(a, bv, acc, 0, 0, 0);
    }
#pragma unroll
    for (int r = 0; r < 4; ++r) {
        int nd = n0 + quad * 4 + r;
        if (nd < n_nodes)
            hout[(size_t)nd * HID + wave * 16 + m] =
                __float2half(acc[r] * dinv[nd]);
    }
}

// ---- pass 2: agg h2 via dwordx4 slices + relu2 + z epilogue -------------

__global__ __launch_bounds__(256) void k_agg_z(
        const int* __restrict__ rowptr, const int* __restrict__ csr,
        const __half* __restrict__ h, const float* __restrict__ b,
        const float* __restrict__ dinv, const float* __restrict__ W3l,
        float2* __restrict__ zbuf, int n_nodes) {
    const int t = threadIdx.x;
    const int n0 = blockIdx.x * 16;
    const int nl = t >> 4;          // local node 0..15
    const int node = n0 + nl;
    const int l16 = t & 15;
    const int cb = l16 & 7;         // my 8-channel block (16B slice)
    const int hf = l16 >> 3;        // even/odd edge half
    const int4* h16 = (const int4*)h;   // 16B units; row = 8 units

    float w3l0[8], w3l1[8], bb8[8];
#pragma unroll
    for (int i = 0; i < 8; ++i) {
        w3l0[i] = W3l[(cb * 8 + i) * 2 + 0];
        w3l1[i] = W3l[(cb * 8 + i) * 2 + 1];
        bb8[i] = b[cb * 8 + i];
    }

    float acc8[8];
#pragma unroll
    for (int i = 0; i < 8; ++i) acc8[i] = 0.0f;

    float dv = 0.0f;
    if (node < n_nodes) {
        int beg = rowptr[node], end = rowptr[node + 1];
        dv = dinv[node];
        if (hf == 0)                       // self h' slice, once
            add_h8(acc8, h16[(size_t)node * 8 + cb]);
        int j = beg;
        for (; j + 7 < end; j += 8) {      // 8 edges: 1 csr + 4 gathers
            int e8 = csr[j + (l16 & 7)];
            int4 r[4];
#pragma unroll
            for (int q = 0; q < 4; ++q) {
                int sid = __shfl(e8, 2 * q + hf, 8);
                r[q] = h16[(size_t)sid * 8 + cb];
            }
#pragma unroll
            for (int q = 0; q < 4; ++q) add_h8(acc8, r[q]);
        }
        if (j + 3 < end) {                 // 4 edges: 2 gathers
            int e4 = csr[j + (l16 & 3)];
            int4 r[2];
#pragma unroll
            for (int q = 0; q < 2; ++q) {
                int sid = __shfl(e4, 2 * q + hf, 4);
                r[q] = h16[(size_t)sid * 8 + cb];
            }
            add_h8(acc8, r[0]);
            add_h8(acc8, r[1]);
            j += 4;
        }
        for (; j < end; ++j)               // <=3 edges: half 0 only
            if (hf == 0) add_h8(acc8, h16[(size_t)csr[j] * 8 + cb]);
    }
    // combine even/odd halves (lanes l16 and l16^8 hold same cb)
#pragma unroll
    for (int i = 0; i < 8; ++i) acc8[i] += __shfl_xor(acc8[i], 8, 16);
    // relu2 + dot with W3l columns
    float p0 = 0.0f, p1 = 0.0f;
#pragma unroll
    for (int i = 0; i < 8; ++i) {
        float v = fmaxf(bb8[i] + dv * acc8[i], 0.0f);
        p0 += v * w3l0[i];
        p1 += v * w3l1[i];
    }
#pragma unroll
    for (int o = 4; o; o >>= 1) {
        p0 += __shfl_xor(p0, o, 16);
        p1 += __shfl_xor(p1, o, 16);
    }
    if (node < n_nodes && l16 == 0)
        zbuf[node] = make_float2(p0 * dv, p1 * dv);
}

// ---- pass 3: aggregate z (8B rows, L2-resident) -> graph partials -------

__global__ __launch_bounds__(256) void k_zagg_part(
        const int* __restrict__ rowptr, const int* __restrict__ csr,
        const float2* __restrict__ zbuf, const float* __restrict__ dinv,
        const int* __restrict__ batch, float* __restrict__ partv,
        int* __restrict__ partg, float* __restrict__ gsum, int n_nodes) {
    __shared__ float2 ys[16];
    __shared__ int bg[16];
    const int t = threadIdx.x;
    const int n0 = blockIdx.x * 16;
    const int nl = t >> 4;
    const int node = n0 + nl;
    const int q = t & 15;

    if (t < 16) {
        int nd = n0 + t;
        bg[t] = (nd < n_nodes) ? batch[nd] : -1;
    }

    float2 yv = make_float2(0.0f, 0.0f);
    if (node < n_nodes) {
        int beg = rowptr[node], end = rowptr[node + 1];
        float2 acc = make_float2(0.0f, 0.0f);
        if (q == 0) acc = zbuf[node];          // self-loop
        int j = beg;
        for (; j + 15 < end; j += 16) {        // 16 edges/iter, 1 gather instr
            int e = csr[j + q];
            float2 v = zbuf[e];
            acc.x += v.x; acc.y += v.y;
        }
        int rem = end - j;
        if (q < rem) {
            int e = csr[j + q];
            float2 v = zbuf[e];
            acc.x += v.x; acc.y += v.y;
        }
#pragma unroll
        for (int o = 8; o; o >>= 1) {
            acc.x += __shfl_xor(acc.x, o, 16);
            acc.y += __shfl_xor(acc.y, o, 16);
        }
        float dv = dinv[node];
        yv = make_float2(acc.x * dv, acc.y * dv);
    }
    if (q == 0) ys[nl] = yv;
    __syncthreads();

    if (t == 0) {           // run-length reduce 16 nodes -> <=2 graph slots
        const int g0 = bg[0];
        const int g15 = bg[15];
        float2 s0 = make_float2(0.0f, 0.0f), s1 = make_float2(0.0f, 0.0f);
        for (int i = 0; i < 16; ++i) {
            int g = bg[i];
            float2 v = ys[i];
            if (g == g0) { s0.x += v.x; s0.y += v.y; }
            else if (g == g15) { s1.x += v.x; s1.y += v.y; }
            else if (g >= 0) {                 // ~never (graph <=14 nodes)
                atomicAdd(&gsum[g * 2 + 0], v.x);
                atomicAdd(&gsum[g * 2 + 1], v.y);
            }
        }
        partv[(size_t)blockIdx.x * 4 + 0] = s0.x;
        partv[(size_t)blockIdx.x * 4 + 1] = s0.y;
        partv[(size_t)blockIdx.x * 4 + 2] = s1.x;
        partv[(size_t)blockIdx.x * 4 + 3] = s1.y;
        partg[blockIdx.x * 2 + 0] = g0;
        partg[blockIdx.x * 2 + 1] = (g15 != g0) ? g15 : -1;
    }
}

// ---- pool over float2 partials + head bias: one block per graph ---------

__global__ __launch_bounds__(256) void k_pool_head(
        const float* __restrict__ partv, const int* __restrict__ partg,
        const float* __restrict__ gsum, const int* __restrict__ batch,
        const float* __restrict__ b3, const float* __restrict__ Wl,
        const float* __restrict__ bl, float* __restrict__ out, int n_nodes) {
    int g = blockIdx.x;
    int lo = 0, hi = n_nodes;
    while (lo < hi) { int m = (lo + hi) >> 1; if (batch[m] < g) lo = m + 1; else hi = m; }
    int nstart = lo;
    hi = n_nodes;
    while (lo < hi) { int m = (lo + hi) >> 1; if (batch[m] < g + 1) lo = m + 1; else hi = m; }
    int nend = lo;

    const int t = threadIdx.x;
    float ax = 0.0f, ay = 0.0f;
    if (nend > nstart) {
        int b0 = nstart >> 4, b1 = (nend - 1) >> 4;
        for (int b = b0 + t; b <= b1; b += 256) {
            if (partg[b * 2 + 0] == g) { ax += partv[(size_t)b * 4 + 0]; ay += partv[(size_t)b * 4 + 1]; }
            if (partg[b * 2 + 1] == g) { ax += partv[(size_t)b * 4 + 2]; ay += partv[(size_t)b * 4 + 3]; }
        }
    }
    __shared__ float rx[256], ry[256];
    rx[t] = ax; ry[t] = ay;
    __syncthreads();
    for (int s2 = 128; s2; s2 >>= 1) {
        if (t < s2) { rx[t] += rx[t + s2]; ry[t] += ry[t + s2]; }
        __syncthreads();
    }
    if (t < 2) {
        float cntf = fmaxf((float)(nend - nstart), 1.0f);
        float s = ((t == 0) ? rx[0] : ry[0]) + gsum[g * 2 + t];
        float hb = 0.0f;                     // b3 @ Wl (column t)
        for (int c = 0; c < HID; ++c) hb += b3[c] * Wl[c * 2 + t];
        out[g * 2 + t] = s / cntf + hb + bl[t];
    }
}

// -------------------------------------------------------------------------

extern "C" void kernel_launch(void* const* d_in, const int* in_sizes, int n_in,
                              void* d_out, int out_size, void* d_ws, size_t ws_size,
                              hipStream_t stream) {
    const float* x     = (const float*)d_in[0];
    const int*   ei    = (const int*)d_in[1];
    const int*   batch = (const int*)d_in[2];
    const float* W1    = (const float*)d_in[3];
    const float* b1    = (const float*)d_in[4];
    const float* W2    = (const float*)d_in[5];
    const float* b2    = (const float*)d_in[6];
    const float* W3    = (const float*)d_in[7];
    const float* b3    = (const float*)d_in[8];
    const float* Wl    = (const float*)d_in[9];
    const float* bl    = (const float*)d_in[10];
    float* out = (float*)d_out;

    const int N = in_sizes[0] / 7;     // 100000
    const int E = in_sizes[1] / 2;     // 1250000
    const int* src = ei;
    const int* dst = ei + E;

    const int nbkt   = (N + BKTSZ - 1) >> BKTSH;          // 196
    const int nchunk = (E + CHUNK - 1) / CHUNK;           // 306
    const int lenH   = nbkt * nchunk;
    const int nscan  = (lenH + 1023) / 1024;              // 59 (<=64)

    char* ws = (char*)d_ws;
    size_t off = 0;
    auto carve = [&](size_t bytes) {
        void* p = ws + off;
        off = (off + bytes + 255) & ~(size_t)255;
        return p;
    };
    int*    H      = (int*)carve((size_t)lenH * 4);
    int*    Hs     = (int*)carve((size_t)lenH * 4);
    int*    bsum   = (int*)carve(512 * 4);
    int*    packed = (int*)carve((size_t)E * 4);
    int*    csr    = (int*)carve((size_t)E * 4);
    int*    rowptr = (int*)carve((size_t)(N + 1) * 4);
    float*  dinv   = (float*)carve((size_t)N * 4);
    __half* Wf2    = (__half*)carve(4096 * 2);
    float*  W3l    = (float*)carve(128 * 4);
    float*  gsum   = (float*)carve((size_t)NGRAPHS * 2 * 4);
    float*  xt     = (float*)carve((size_t)(N + 64) * 8 * 4);     // padded x~
    __half* bufB   = (__half*)carve((size_t)(N + 64) * HID * 2);  // +pad rows
    float2* zbuf   = (float2*)carve((size_t)(N + 64) * 8);

    const int nb_agg = (N + 15) / 16;      // 6250
    float* partv = (float*)carve((size_t)nb_agg * 4 * 4);
    int*   partg = (int*)carve((size_t)nb_agg * 2 * 4);

    // ---- CSR build (LDS counting sort, 3-pass scan pipeline)
    k_hist<<<nchunk, 256, 0, stream>>>(dst, W2, W3, Wl, Wf2, W3l, H, gsum,
                                       E, nbkt, nchunk);
    k_scan<<<nscan, 256, 0, stream>>>(H, Hs, bsum, lenH);
    k_scatter<<<nchunk, 256, 0, stream>>>(src, dst, Hs, bsum, packed,
                                          E, nbkt, nchunk, nscan);
    // csr_build also emits x~ = x*dinv (padded 8-float rows)
    k_csr_build<<<nbkt, 256, 0, stream>>>(packed, Hs, bsum, rowptr, dinv, csr,
                                          x, xt, E, N, nbkt, nchunk, nscan);

    // ---- fused layers 1+2 (x~ agg + W1 matvec + W2 MFMA) -> bufB
    k_aggx_gemm<<<nb_agg, 256, 0, stream>>>(rowptr, csr, xt, b1, dinv, W1,
                                            Wf2, bufB, N);
    // ---- pass 2: agg bufB + relu2 + z = dinv*(relu2@W3l) (8B/node)
    k_agg_z<<<nb_agg, 256, 0, stream>>>(rowptr, csr, bufB, b2, dinv, W3l,
                                        zbuf, N);
    // ---- pass 3: agg z (8B rows) -> per-block graph partials
    k_zagg_part<<<nb_agg, 256, 0, stream>>>(rowptr, csr, zbuf, dinv, batch,
                                            partv, partg, gsum, N);

    // ---- pool over partials + head (one block per graph)
    k_pool_head<<<NGRAPHS, 256, 0, stream>>>(partv, partg, gsum, batch,
                                             b3, Wl, bl, out, N);
}